// Round 2
// baseline (189.460 us; speedup 1.0000x reference)
//
#include <hip/hip_runtime.h>

typedef __attribute__((ext_vector_type(8))) short short8;
typedef __attribute__((ext_vector_type(4))) float f32x4;
typedef __attribute__((ext_vector_type(4))) int i32x4;

typedef __attribute__((address_space(1))) const unsigned int gas_u32;
typedef __attribute__((address_space(3))) unsigned int las_u32;

#define HW 56
#define P_IMG 3136          // 56*56
#define XSTRIDE 802816      // 256*3136
#define OUT_C 256
#define K_TOT 1152
#define KT_N 18             // 1152/64
#define BM 128
#define NBLK 392            // 50176/128

__device__ __forceinline__ unsigned short f2bf_bits(float f) {
    unsigned u = __builtin_bit_cast(unsigned, f);
    return (unsigned short)((u + 0x7FFFu + ((u >> 16) & 1u)) >> 16);
}

// W prep: gw[t][oc][e] = bf16( w[ t*64 + (e ^ ((oc&7)<<3)) ][oc] )
// -> linear global_load_lds into [256 oc][64 k] LDS rows yields the
//    XOR-swizzled layout the fragment reads expect (swizzle baked in).
__global__ __launch_bounds__(256) void prep_w_kernel(const float* __restrict__ w,
                                                     unsigned short* __restrict__ gw) {
    int i = blockIdx.x * 256 + threadIdx.x;       // 294912 = 18*256*64
    int e = i & 63;
    int oc = (i >> 6) & 255;
    int t = i >> 14;
    int ksrc = t * 64 + (e ^ ((oc & 7) << 3));
    gw[i] = f2bf_bits(w[ksrc * 256 + oc]);
}

// idx prep: pack biased address delta (+57 so >=0) and (dh*3+dw) in bits 20..23
__global__ __launch_bounds__(256) void prep_idx_kernel(const int* __restrict__ idx,
                                                       int* __restrict__ didx) {
    int i = blockIdx.x * 256 + threadIdx.x;
    if (i < K_TOT) {
        int v = idx[i];
        int c = v / 9;
        int rr = v - c * 9;           // dh*3+dw
        int dh = rr / 3;
        int dw = rr - dh * 3;
        int delta_b = c * P_IMG + (dh - 1) * HW + (dw - 1) + 57;
        didx[i] = delta_b | (rr << 20);
    }
}

__global__ __launch_bounds__(512, 2) void mconv_mfma(
        const float* __restrict__ x,
        const unsigned short* __restrict__ gw,
        const int* __restrict__ didx,
        float* __restrict__ out) {
    __shared__ __attribute__((aligned(16))) char smem[98304];
    char* const A0 = smem;              // [128 m][64 k] bf16, swizzled
    char* const A1 = smem + 16384;
    char* const W0 = smem + 32768;      // [256 oc][64 k] bf16, swizzled
    char* const W1 = smem + 65536;

    const int tid = threadIdx.x;
    const int wv  = tid >> 6;
    const int ln  = tid & 63;
    const int lhi = ln >> 4;
    const int llo = ln & 15;
    const int oc0 = (wv >> 1) * 64;     // wave tile: 64 oc x 64 m
    const int mw0 = (wv & 1) * 64;

    const int bid = blockIdx.x;
    const int m0 = ((bid & 7) * 49 + (bid >> 3)) * BM;   // XCD swizzle, 392=8*49

    // A-staging coords: thread -> (row sr, k-quarter sq)
    const int sr = tid >> 2;
    const int sq = tid & 3;
    const int mrow = m0 + sr;
    const int nimg = mrow / P_IMG;
    const int p = mrow - nimg * P_IMG;
    const int oh = p / HW;
    const int ow = p - oh * HW;
    const int gbase = nimg * XSTRIDE + p - 57;   // -57 cancels delta bias
    const int ohm1 = oh - 1, owm1 = ow - 1;

    // 9-bit pad-validity LUT over (dh,dw)
    unsigned oklut = 0;
    #pragma unroll
    for (int dh = 0; dh < 3; ++dh)
        #pragma unroll
        for (int dw = 0; dw < 3; ++dw) {
            bool okh = (unsigned)(ohm1 + dh) < (unsigned)HW;
            bool okw = (unsigned)(owm1 + dw) < (unsigned)HW;
            if (okh && okw) oklut |= (1u << (dh * 3 + dw));
        }

    // ---- prologue: stage tile 0 ----
    {
        float tv[16];
        unsigned okm = 0;
        const int kbase = sq * 16;
        #pragma unroll
        for (int q4 = 0; q4 < 4; ++q4) {
            i32x4 d = *(const i32x4*)(didx + kbase + q4 * 4);
            int vvv[4] = { d.x, d.y, d.z, d.w };
            #pragma unroll
            for (int jj = 0; jj < 4; ++jj) {
                int j = q4 * 4 + jj;
                int v = vvv[jj];
                int addr = gbase + (v & 0xFFFFF);
                unsigned ok = (oklut >> (v >> 20)) & 1u;
                tv[j] = x[ok ? addr : 0];
                okm |= ok << j;
            }
        }
        #pragma unroll
        for (int rd = 0; rd < 4; ++rd) {
            const char* g = (const char*)gw + rd * 8192 + tid * 16;
            __builtin_amdgcn_global_load_lds((gas_u32*)g, (las_u32*)(W0 + rd * 8192 + tid * 16), 16, 0, 0);
        }
        short8 pk0, pk1;
        #pragma unroll
        for (int j = 0; j < 8; ++j) {
            pk0[j] = (short)(((okm >> j) & 1u) ? f2bf_bits(tv[j]) : (unsigned short)0);
            pk1[j] = (short)(((okm >> (j + 8)) & 1u) ? f2bf_bits(tv[j + 8]) : (unsigned short)0);
        }
        const int swz = (sr & 7) << 4;
        char* rowp = A0 + sr * 128;
        *(short8*)(rowp + ((sq * 32) ^ swz)) = pk0;
        *(short8*)(rowp + ((sq * 32 + 16) ^ swz)) = pk1;
    }
    __syncthreads();

    f32x4 acc[4][4] = {};   // [ni][mi], D[oc][m]

    for (int kt = 0; kt < KT_N; ++kt) {
        char* const Ac = (kt & 1) ? A1 : A0;
        char* const An = (kt & 1) ? A0 : A1;
        char* const Wc = (kt & 1) ? W1 : W0;
        char* const Wn = (kt & 1) ? W0 : W1;

        float tv[16];
        unsigned okm = 0;
        const bool do_stage = (kt + 1 < KT_N);
        if (do_stage) {
            // issue gather loads for next tile (results consumed after MFMA)
            const int kbase = (kt + 1) * 64 + sq * 16;
            #pragma unroll
            for (int q4 = 0; q4 < 4; ++q4) {
                i32x4 d = *(const i32x4*)(didx + kbase + q4 * 4);
                int vvv[4] = { d.x, d.y, d.z, d.w };
                #pragma unroll
                for (int jj = 0; jj < 4; ++jj) {
                    int j = q4 * 4 + jj;
                    int v = vvv[jj];
                    int addr = gbase + (v & 0xFFFFF);
                    unsigned ok = (oklut >> (v >> 20)) & 1u;
                    tv[j] = x[ok ? addr : 0];
                    okm |= ok << j;
                }
            }
            // async W stage into next buffer
            #pragma unroll
            for (int rd = 0; rd < 4; ++rd) {
                const char* g = (const char*)gw + (kt + 1) * 32768 + rd * 8192 + tid * 16;
                __builtin_amdgcn_global_load_lds((gas_u32*)g, (las_u32*)(Wn + rd * 8192 + tid * 16), 16, 0, 0);
            }
        }
        __builtin_amdgcn_sched_barrier(0);  // keep load issue above the MFMA block

        // compute current tile: D[oc][m] += W^T-tile * A^T-tile
        #pragma unroll
        for (int ks = 0; ks < 2; ++ks) {
            short8 wf[4], af[4];
            #pragma unroll
            for (int i = 0; i < 4; ++i) {
                const int row = oc0 + i * 16 + llo;
                wf[i] = *(const short8*)(Wc + row * 128 + ((ks * 64 + lhi * 16) ^ ((row & 7) << 4)));
            }
            #pragma unroll
            for (int i = 0; i < 4; ++i) {
                const int row = mw0 + i * 16 + llo;
                af[i] = *(const short8*)(Ac + row * 128 + ((ks * 64 + lhi * 16) ^ ((row & 7) << 4)));
            }
            #pragma unroll
            for (int ni = 0; ni < 4; ++ni)
                #pragma unroll
                for (int mi = 0; mi < 4; ++mi)
                    acc[ni][mi] = __builtin_amdgcn_mfma_f32_16x16x32_bf16(wf[ni], af[mi], acc[ni][mi], 0, 0, 0);
        }

        if (do_stage) {
            // late write: select/convert/ds_write (loads hid under MFMA)
            short8 pk0, pk1;
            #pragma unroll
            for (int j = 0; j < 8; ++j) {
                pk0[j] = (short)(((okm >> j) & 1u) ? f2bf_bits(tv[j]) : (unsigned short)0);
                pk1[j] = (short)(((okm >> (j + 8)) & 1u) ? f2bf_bits(tv[j + 8]) : (unsigned short)0);
            }
            const int swz = (sr & 7) << 4;
            char* rowp = An + sr * 128;
            *(short8*)(rowp + ((sq * 32) ^ swz)) = pk0;
            *(short8*)(rowp + ((sq * 32 + 16) ^ swz)) = pk1;
        }
        __syncthreads();
    }

    // ---- epilogue: D[oc][m] -> out[n][oc][p], m contiguous across lanes ----
    #pragma unroll
    for (int mi = 0; mi < 4; ++mi) {
        const int mg = m0 + mw0 + mi * 16 + llo;
        const int n = mg / P_IMG;
        const int pp = mg - n * P_IMG;
        float* ob = out + n * XSTRIDE + pp;
        #pragma unroll
        for (int ni = 0; ni < 4; ++ni) {
            const int ocb = (oc0 + ni * 16 + lhi * 4) * P_IMG;
            #pragma unroll
            for (int j = 0; j < 4; ++j)
                ob[ocb + j * P_IMG] = acc[ni][mi][j];
        }
    }
}

extern "C" void kernel_launch(void* const* d_in, const int* in_sizes, int n_in,
                              void* d_out, int out_size, void* d_ws, size_t ws_size,
                              hipStream_t stream) {
    const float* x  = (const float*)d_in[0];
    const float* w  = (const float*)d_in[1];
    const int* idx  = (const int*)d_in[2];
    float* out = (float*)d_out;

    unsigned short* gw = (unsigned short*)d_ws;                    // 589824 B
    int* didx = (int*)((char*)d_ws + K_TOT * OUT_C * 2);           // 4608 B

    prep_w_kernel<<<dim3(1152), dim3(256), 0, stream>>>(w, gw);
    prep_idx_kernel<<<dim3(5), dim3(256), 0, stream>>>(idx, didx);
    mconv_mfma<<<dim3(NBLK), dim3(512), 0, stream>>>(x, gw, didx, out);
}